// Round 13
// baseline (948.001 us; speedup 1.0000x reference)
//
#include <hip/hip_runtime.h>
#include <hip/hip_bf16.h>
#include <math.h>

#define NROWS 8192
#define MAXNNZ 512

typedef __attribute__((ext_vector_type(8))) short short8v;   // 8 bf16 = 4 VGPR
typedef __attribute__((ext_vector_type(4))) float floatx4;

__device__ inline void storev(float* p, float v) { *p = v; }
__device__ inline void storev(__hip_bfloat16* p, float v) { *p = __float2bfloat16(v); }

// ---------------- CSR build: float4 scan + wave-aggregated compaction ----------------
// One LDS atomic per wave per element-slot (was ~8 serialized same-address atomics).
// Column order within a row changes vs sequential — only reassociates the SpMM sum.
__global__ void build_csr_kernel(const float* __restrict__ adj, int* __restrict__ cols,
                                 int* __restrict__ cnt, float* __restrict__ dvec) {
    int row = blockIdx.x;
    __shared__ int lcnt;
    if (threadIdx.x == 0) lcnt = 0;
    __syncthreads();
    const float* arow = adj + (size_t)row * NROWS;
    int* crow = cols + (size_t)row * MAXNNZ;
    int tid = threadIdx.x;
    int lane = tid & 63;
#pragma unroll
    for (int j = 0; j < NROWS / 1024; ++j) {
        int c = (j * 256 + tid) * 4;
        float4 v = *reinterpret_cast<const float4*>(&arow[c]);
        float vv[4] = {v.x, v.y, v.z, v.w};
#pragma unroll
        for (int e = 0; e < 4; ++e) {
            bool nz = vv[e] != 0.0f;
            unsigned long long m = __ballot(nz);
            int tot = __popcll(m);
            if (tot) {                               // wave-uniform branch
                int pre = __popcll(m & ((1ull << lane) - 1));
                int base = 0;
                if (lane == 0) base = atomicAdd(&lcnt, tot);
                base = __shfl(base, 0);
                if (nz) {
                    int p = base + pre;
                    if (p < MAXNNZ) crow[p] = c + e;
                }
            }
        }
    }
    __syncthreads();
    if (threadIdx.x == 0) {
        int n = lcnt; if (n > MAXNNZ) n = MAXNNZ;
        cnt[row] = n;
        dvec[row] = rsqrtf((float)lcnt);
    }
}

// ---------------- cast x -> bf16, K padded 784->800 with zeros ----------------
__global__ void cast_x_kernel(const float* __restrict__ x, __hip_bfloat16* __restrict__ xb) {
    int row = blockIdx.x;
    int tid = threadIdx.x;
    const float* src = x + (size_t)row * 784;
    __hip_bfloat16* dst = xb + (size_t)row * 800;
    for (int c = tid; c < 800; c += 256)
        dst[c] = (c < 784) ? __float2bfloat16(src[c]) : __float2bfloat16(0.0f);
}

// ---------------- weight prep ----------------
__global__ void prep_kernel(const float* __restrict__ Wg1,
                            const float* __restrict__ Wd11, const float* __restrict__ Wd12,
                            const float* __restrict__ bd11, const float* __restrict__ bd12,
                            const float* __restrict__ Wd21, const float* __restrict__ Wd22,
                            const float* __restrict__ bd21, const float* __restrict__ bd22,
                            __hip_bfloat16* __restrict__ Wg1T, __hip_bfloat16* __restrict__ Wcat1T,
                            float* __restrict__ bcat1, float* __restrict__ Wcat2,
                            float* __restrict__ bcat2) {
    int idx = blockIdx.x * 256 + threadIdx.x;
    if (idx < 256 * 800) {                       // Wg1T[n][k]
        int n = idx / 800, k = idx % 800;
        Wg1T[idx] = __float2bfloat16(k < 784 ? Wg1[k * 256 + n] : 0.0f);
        return;
    }
    idx -= 256 * 800;
    if (idx < 384 * 256) {                       // Wcat1T[n][k]
        int n = idx / 256, k = idx % 256;
        float v = (n < 128) ? Wd11[k * 128 + n] : Wd12[k * 256 + (n - 128)];
        Wcat1T[idx] = __float2bfloat16(v);
        return;
    }
    idx -= 384 * 256;
    if (idx < 384) { bcat1[idx] = (idx < 128) ? bd11[idx] : bd12[idx - 128]; return; }
    idx -= 384;
    if (idx < 128 * 192) {
        int r = idx / 192, c = idx % 192;
        Wcat2[idx] = (c < 128) ? Wd21[r * 128 + c] : Wd22[r * 64 + (c - 128)];
        return;
    }
    idx -= 128 * 192;
    if (idx < 192) { bcat2[idx] = (idx < 128) ? bd21[idx] : bd22[idx - 128]; return; }
}

// ---------------- MFMA bf16 GEMM: C = A[MxK]bf16 @ (BT[NxK]bf16)^T (+bias) ----------------
// tile 128(M) x 64(N), K-step 32, 256 thr = 4 waves. (HW-verified round 10/11.)
template<typename OUT>
__global__ void gemm_mfma_kernel(const __hip_bfloat16* __restrict__ A,
                                 const __hip_bfloat16* __restrict__ BT,
                                 const float* __restrict__ bias,
                                 OUT* __restrict__ C, int K,
                                 int lda, int ldb, int ldc) {
    __shared__ __hip_bfloat16 As[128][40];   // row stride 80B
    __shared__ __hip_bfloat16 Bs[64][40];
    int tid = threadIdx.x;
    int w = tid >> 6, lane = tid & 63;
    int row0 = blockIdx.y * 128, col0 = blockIdx.x * 64;
    int lrow = lane & 15, kb = (lane >> 4) * 8;
    floatx4 acc[2][4] = {};
    int ar = tid >> 1, akh = (tid & 1) * 16;
    int bn = tid >> 2, bkh = (tid & 3) * 8;
    for (int k0 = 0; k0 < K; k0 += 32) {
        {
            const float4* src = reinterpret_cast<const float4*>(&A[(size_t)(row0 + ar) * lda + k0 + akh]);
            float4 v0 = src[0], v1 = src[1];
            *reinterpret_cast<float4*>(&As[ar][akh]) = v0;
            *reinterpret_cast<float4*>(&As[ar][akh + 8]) = v1;
        }
        {
            float4 v = *reinterpret_cast<const float4*>(&BT[(size_t)(col0 + bn) * ldb + k0 + bkh]);
            *reinterpret_cast<float4*>(&Bs[bn][bkh]) = v;
        }
        __syncthreads();
        short8v af[2], bf[4];
#pragma unroll
        for (int mi = 0; mi < 2; ++mi)
            af[mi] = *reinterpret_cast<const short8v*>(&As[w * 32 + mi * 16 + lrow][kb]);
#pragma unroll
        for (int ni = 0; ni < 4; ++ni)
            bf[ni] = *reinterpret_cast<const short8v*>(&Bs[ni * 16 + lrow][kb]);
#pragma unroll
        for (int mi = 0; mi < 2; ++mi)
#pragma unroll
            for (int ni = 0; ni < 4; ++ni)
                acc[mi][ni] = __builtin_amdgcn_mfma_f32_16x16x32_bf16(af[mi], bf[ni], acc[mi][ni], 0, 0, 0);
        __syncthreads();
    }
#pragma unroll
    for (int mi = 0; mi < 2; ++mi) {
#pragma unroll
        for (int ni = 0; ni < 4; ++ni) {
            int gcol = col0 + ni * 16 + (lane & 15);
            float bb = bias ? bias[gcol] : 0.0f;
#pragma unroll
            for (int r = 0; r < 4; ++r) {
                int grow = row0 + w * 32 + mi * 16 + (lane >> 4) * 4 + r;
                storev(&C[(size_t)grow * ldc + gcol], acc[mi][ni][r] + bb);
            }
        }
    }
}

// ---------------- MFMA bf16 pooling: C[M,N] += sum_k A[k][m]*B[k][n] (atomic f32) ----------------
__global__ void gemm_atn_mfma_kernel(const __hip_bfloat16* __restrict__ A,
                                     const __hip_bfloat16* __restrict__ B,
                                     float* __restrict__ C, int M, int N, int K, int KC,
                                     int lda, int ldb, int ldc) {
    __shared__ unsigned short At[64][40];   // [m][k]
    __shared__ unsigned short Bt[64][40];   // [n][k]
    int tid = threadIdx.x;
    int w = tid >> 6, lane = tid & 63;
    int m0 = blockIdx.y * 64, n0 = blockIdx.x * 64;
    int kbeg = blockIdx.z * KC;
    int kend = kbeg + KC; if (kend > K) kend = K;
    int lrow = lane & 15, kb = (lane >> 4) * 8;
    floatx4 acc[4] = {};
    int kk = tid >> 3;            // 0..31
    int eg = (tid & 7) * 8;       // 0..56
    for (int k0 = kbeg; k0 < kend; k0 += 32) {
        {
            unsigned short v[8];
            *reinterpret_cast<float4*>(v) = *reinterpret_cast<const float4*>(
                &A[(size_t)(k0 + kk) * lda + m0 + eg]);
#pragma unroll
            for (int e = 0; e < 8; ++e) At[eg + e][kk] = v[e];
        }
        {
            unsigned short v[8];
            *reinterpret_cast<float4*>(v) = *reinterpret_cast<const float4*>(
                &B[(size_t)(k0 + kk) * ldb + n0 + eg]);
#pragma unroll
            for (int e = 0; e < 8; ++e) Bt[eg + e][kk] = v[e];
        }
        __syncthreads();
        short8v af = *reinterpret_cast<const short8v*>(&At[w * 16 + lrow][kb]);
#pragma unroll
        for (int ni = 0; ni < 4; ++ni) {
            short8v bfr = *reinterpret_cast<const short8v*>(&Bt[ni * 16 + lrow][kb]);
            acc[ni] = __builtin_amdgcn_mfma_f32_16x16x32_bf16(af, bfr, acc[ni], 0, 0, 0);
        }
        __syncthreads();
    }
#pragma unroll
    for (int ni = 0; ni < 4; ++ni) {
        int gcol = n0 + ni * 16 + lrow;
#pragma unroll
        for (int r = 0; r < 4; ++r) {
            int grow = m0 + w * 16 + (lane >> 4) * 4 + r;
            atomicAdd(&C[(size_t)grow * ldc + gcol], acc[ni][r]);
        }
    }
}

// ---------------- col-sliced SpMM, scalar CSR metadata (no LDS, no barriers) ----------------
// crow[i]/dvec[c] addresses are wave-uniform -> compiler emits s_load (scalar pipe).
// Vector pipe per gather: global_load_ushort + cvt + fma only.
__global__ void spmm_bf16_sliced_kernel(const int* __restrict__ cols, const int* __restrict__ cnt,
                                        const float* __restrict__ dvec,
                                        const __hip_bfloat16* __restrict__ H,
                                        const float* __restrict__ bias,
                                        __hip_bfloat16* __restrict__ out,
                                        int ldh, int ldo) {
    int row = blockIdx.x;
    int cb = blockIdx.y * 128;
    int tid = threadIdx.x;
    int n = cnt[row];
    const int* crow = cols + (size_t)row * MAXNNZ;
    const __hip_bfloat16* Hs = H + cb + tid;
    float acc = 0.0f;
    int i = 0;
    for (; i + 8 <= n; i += 8) {
        int c0 = crow[i+0], c1 = crow[i+1], c2 = crow[i+2], c3 = crow[i+3];
        int c4 = crow[i+4], c5 = crow[i+5], c6 = crow[i+6], c7 = crow[i+7];
        float w0 = dvec[c0], w1 = dvec[c1], w2 = dvec[c2], w3 = dvec[c3];
        float w4 = dvec[c4], w5 = dvec[c5], w6 = dvec[c6], w7 = dvec[c7];
        float h0 = __bfloat162float(Hs[c0 * ldh]);
        float h1 = __bfloat162float(Hs[c1 * ldh]);
        float h2 = __bfloat162float(Hs[c2 * ldh]);
        float h3 = __bfloat162float(Hs[c3 * ldh]);
        float h4 = __bfloat162float(Hs[c4 * ldh]);
        float h5 = __bfloat162float(Hs[c5 * ldh]);
        float h6 = __bfloat162float(Hs[c6 * ldh]);
        float h7 = __bfloat162float(Hs[c7 * ldh]);
        acc += w0*h0 + w1*h1 + w2*h2 + w3*h3 + w4*h4 + w5*h5 + w6*h6 + w7*h7;
    }
    for (; i < n; ++i) {
        int c = crow[i];
        acc += dvec[c] * __bfloat162float(Hs[c * ldh]);
    }
    float r = dvec[row] * acc;
    if (bias) r += bias[cb + tid];
    out[(size_t)row * ldo + cb + tid] = __float2bfloat16(r);
}

// ---------------- softmax over bf16 row (256 cols), bf16 out ----------------
__global__ void softmax_bf16_kernel(const __hip_bfloat16* __restrict__ in,
                                    __hip_bfloat16* __restrict__ out) {
    int row = blockIdx.x;
    int tid = threadIdx.x;
    __shared__ float red[256];
    float v = __bfloat162float(in[(size_t)row * 384 + 128 + tid]);
    red[tid] = v; __syncthreads();
    for (int s = 128; s > 0; s >>= 1) {
        if (tid < s) red[tid] = fmaxf(red[tid], red[tid + s]);
        __syncthreads();
    }
    float m = red[0]; __syncthreads();
    float e = expf(v - m);
    red[tid] = e; __syncthreads();
    for (int s = 128; s > 0; s >>= 1) {
        if (tid < s) red[tid] += red[tid + s];
        __syncthreads();
    }
    out[(size_t)row * 256 + tid] = __float2bfloat16(e / red[0]);
}

// ---------------- Tiled f32 GEMM (stage 2/3) ----------------
__global__ void gemm_bias_kernel(const float* __restrict__ A, const float* __restrict__ B,
                                 const float* __restrict__ bias, float* __restrict__ C,
                                 int M, int N, int K, int lda, int ldb, int ldc) {
    __shared__ float As[16][68];
    __shared__ float Bs[16][68];
    int tx = threadIdx.x, ty = threadIdx.y;
    int tid = ty * 16 + tx;
    int row0 = blockIdx.y * 64, col0 = blockIdx.x * 64;
    int am = tid >> 2, ak = (tid & 3) * 4;
    int bk = tid >> 4, bn = (tid & 15) * 4;
    float acc[4][4] = {};
    for (int k0 = 0; k0 < K; k0 += 16) {
        int gm = row0 + am;
        float4 va = make_float4(0.f, 0.f, 0.f, 0.f);
        if (gm < M) va = *reinterpret_cast<const float4*>(&A[(size_t)gm * lda + k0 + ak]);
        As[ak + 0][am] = va.x; As[ak + 1][am] = va.y;
        As[ak + 2][am] = va.z; As[ak + 3][am] = va.w;
        float4 vb = *reinterpret_cast<const float4*>(&B[(size_t)(k0 + bk) * ldb + col0 + bn]);
        *reinterpret_cast<float4*>(&Bs[bk][bn]) = vb;
        __syncthreads();
#pragma unroll
        for (int k = 0; k < 16; ++k) {
            float4 a = *reinterpret_cast<const float4*>(&As[k][ty * 4]);
            float4 b = *reinterpret_cast<const float4*>(&Bs[k][tx * 4]);
            float av[4] = {a.x, a.y, a.z, a.w};
            float bv[4] = {b.x, b.y, b.z, b.w};
#pragma unroll
            for (int i = 0; i < 4; ++i)
#pragma unroll
                for (int j = 0; j < 4; ++j)
                    acc[i][j] += av[i] * bv[j];
        }
        __syncthreads();
    }
    float4 bb = make_float4(0.f, 0.f, 0.f, 0.f);
    if (bias) bb = *reinterpret_cast<const float4*>(&bias[col0 + tx * 4]);
#pragma unroll
    for (int i = 0; i < 4; ++i) {
        int gm = row0 + ty * 4 + i;
        if (gm >= M) continue;
        float4 v = make_float4(acc[i][0] + bb.x, acc[i][1] + bb.y,
                               acc[i][2] + bb.z, acc[i][3] + bb.w);
        *reinterpret_cast<float4*>(&C[(size_t)gm * ldc + col0 + tx * 4]) = v;
    }
}

// ---------------- f32 A^T pooling (stage-2 small sizes only) ----------------
__global__ void gemm_atn_kernel(const float* __restrict__ A, const float* __restrict__ B,
                                float* __restrict__ C, int M, int N, int K, int KC,
                                int lda, int ldb, int ldc) {
    __shared__ float As[16][68];
    __shared__ float Bs[16][68];
    int tx = threadIdx.x, ty = threadIdx.y;
    int tid = ty * 16 + tx;
    int row0 = blockIdx.y * 64, col0 = blockIdx.x * 64;
    int kbeg = blockIdx.z * KC;
    int kend = kbeg + KC; if (kend > K) kend = K;
    int ka = tid >> 4, m4 = (tid & 15) * 4;
    int bk = tid >> 4, bn = (tid & 15) * 4;
    float acc[4][4] = {};
    for (int k0 = kbeg; k0 < kend; k0 += 16) {
        int gm = row0 + m4;
        float4 va = make_float4(0.f, 0.f, 0.f, 0.f);
        if (gm < M) va = *reinterpret_cast<const float4*>(&A[(size_t)(k0 + ka) * lda + gm]);
        *reinterpret_cast<float4*>(&As[ka][m4]) = va;
        float4 vb = *reinterpret_cast<const float4*>(&B[(size_t)(k0 + bk) * ldb + col0 + bn]);
        *reinterpret_cast<float4*>(&Bs[bk][bn]) = vb;
        __syncthreads();
#pragma unroll
        for (int k = 0; k < 16; ++k) {
            float4 a = *reinterpret_cast<const float4*>(&As[k][ty * 4]);
            float4 b = *reinterpret_cast<const float4*>(&Bs[k][tx * 4]);
            float av[4] = {a.x, a.y, a.z, a.w};
            float bv[4] = {b.x, b.y, b.z, b.w};
#pragma unroll
            for (int i = 0; i < 4; ++i)
#pragma unroll
                for (int j = 0; j < 4; ++j)
                    acc[i][j] += av[i] * bv[j];
        }
        __syncthreads();
    }
#pragma unroll
    for (int i = 0; i < 4; ++i) {
        int gm = row0 + ty * 4 + i;
        if (gm >= M) continue;
#pragma unroll
        for (int j = 0; j < 4; ++j)
            atomicAdd(&C[(size_t)gm * ldc + col0 + tx * 4 + j], acc[i][j]);
    }
}

// ---------------- row softmax on strided f32 view, in place ----------------
__global__ void softmax_rows_kernel(float* __restrict__ data, int NC, int ld, int off) {
    int row = blockIdx.x;
    float* p = data + (size_t)row * ld + off;
    __shared__ float red[256];
    int tid = threadIdx.x;
    float m = -INFINITY;
    for (int c = tid; c < NC; c += 256) m = fmaxf(m, p[c]);
    red[tid] = m; __syncthreads();
    for (int s = 128; s > 0; s >>= 1) {
        if (tid < s) red[tid] = fmaxf(red[tid], red[tid + s]);
        __syncthreads();
    }
    m = red[0]; __syncthreads();
    float sum = 0.0f;
    for (int c = tid; c < NC; c += 256) sum += expf(p[c] - m);
    red[tid] = sum; __syncthreads();
    for (int s = 128; s > 0; s >>= 1) {
        if (tid < s) red[tid] += red[tid + s];
        __syncthreads();
    }
    float inv = 1.0f / red[0];
    for (int c = tid; c < NC; c += 256) p[c] = expf(p[c] - m) * inv;
}

// ---------------- final: colsum(z3) -> fc -> log_softmax ----------------
__global__ void final_kernel(const float* __restrict__ z3, const float* __restrict__ Wfc,
                             const float* __restrict__ bfc, float* __restrict__ out) {
    __shared__ float v[128];
    __shared__ float o[10];
    int tid = threadIdx.x;
    float a = 0.0f;
#pragma unroll
    for (int i = 0; i < 64; i++) a += z3[i * 128 + tid];
    v[tid] = a;
    __syncthreads();
    if (tid < 10) {
        float s = 0.0f;
        for (int k = 0; k < 128; k++) s += v[k] * Wfc[k * 10 + tid];
        o[tid] = s + bfc[tid];
    }
    __syncthreads();
    if (tid == 0) {
        float m = -INFINITY;
        for (int c = 0; c < 10; c++) m = fmaxf(m, o[c]);
        float s = 0.0f;
        for (int c = 0; c < 10; c++) s += expf(o[c] - m);
        float lse = m + logf(s);
        for (int c = 0; c < 10; c++) out[c] = o[c] - lse;
    }
}

extern "C" void kernel_launch(void* const* d_in, const int* in_sizes, int n_in,
                              void* d_out, int out_size, void* d_ws, size_t ws_size,
                              hipStream_t stream) {
    const float* x      = (const float*)d_in[0];
    const float* adj    = (const float*)d_in[1];
    const float* W_gcn1 = (const float*)d_in[2];
    const float* b_gcn1 = (const float*)d_in[3];
    const float* W_d11  = (const float*)d_in[4];
    const float* b_d11  = (const float*)d_in[5];
    const float* W_d12  = (const float*)d_in[6];
    const float* b_d12  = (const float*)d_in[7];
    const float* W_gcn2 = (const float*)d_in[8];
    const float* b_gcn2 = (const float*)d_in[9];
    const float* W_d21  = (const float*)d_in[10];
    const float* b_d21  = (const float*)d_in[11];
    const float* W_d22  = (const float*)d_in[12];
    const float* b_d22  = (const float*)d_in[13];
    const float* W_gcn3 = (const float*)d_in[14];
    const float* b_gcn3 = (const float*)d_in[15];
    const float* W_d31  = (const float*)d_in[16];
    const float* b_d31  = (const float*)d_in[17];
    // W_d32/b_d32 unused: softmax over a length-1 axis == 1
    const float* W_fc   = (const float*)d_in[20];
    const float* b_fc   = (const float*)d_in[21];

    char* ws = (char*)d_ws;
    size_t off = 0;
    auto alloc = [&](size_t bytes) -> char* {
        char* p = ws + off;
        off = (off + bytes + 255) & ~(size_t)255;
        return p;
    };
    int*   cols  = (int*)  alloc((size_t)NROWS * MAXNNZ * 4);
    int*   cnt   = (int*)  alloc((size_t)NROWS * 4);
    float* dvec  = (float*)alloc((size_t)NROWS * 4);
    __hip_bfloat16* xb     = (__hip_bfloat16*)alloc((size_t)NROWS * 800 * 2);
    __hip_bfloat16* Wg1T   = (__hip_bfloat16*)alloc(256 * 800 * 2);
    __hip_bfloat16* Wcat1T = (__hip_bfloat16*)alloc(384 * 256 * 2);
    __hip_bfloat16* XW1b   = (__hip_bfloat16*)alloc((size_t)NROWS * 256 * 2);
    __hip_bfloat16* x1b    = (__hip_bfloat16*)alloc((size_t)NROWS * 256 * 2);
    __hip_bfloat16* u1b    = (__hip_bfloat16*)alloc((size_t)NROWS * 256 * 2);
    __hip_bfloat16* zcatb  = (__hip_bfloat16*)alloc((size_t)NROWS * 384 * 2);  // [z1(128)|s1pre(256)]
    __hip_bfloat16* ASb    = (__hip_bfloat16*)alloc((size_t)NROWS * 256 * 2);
    __hip_bfloat16* s1b    = (__hip_bfloat16*)alloc((size_t)NROWS * 256 * 2);
    // pooled-zero region (one memset)
    float* Xp    = (float*)alloc(256 * 128 * 4);
    float* adj2  = (float*)alloc(256 * 256 * 4);
    float* Xp2   = (float*)alloc(64 * 128 * 4);
    float* adj3  = (float*)alloc(64 * 64 * 4);
    size_t zero_bytes = 256*128*4 + 256*256*4 + 64*128*4 + 64*64*4;
    float* XW2   = (float*)alloc(256 * 128 * 4);
    float* x2    = (float*)alloc(256 * 128 * 4);
    float* T2cat = (float*)alloc(256 * 192 * 4);
    float* Z2cat = (float*)alloc(256 * 192 * 4);
    float* AS2   = (float*)alloc(256 * 64 * 4);
    float* T30   = (float*)alloc(64 * 128 * 4);
    float* x3    = (float*)alloc(64 * 128 * 4);
    float* T31   = (float*)alloc(64 * 128 * 4);
    float* z3    = (float*)alloc(64 * 128 * 4);
    float* Wcat2 = (float*)alloc(128 * 192 * 4);
    float* bcat1 = (float*)alloc(384 * 4);
    float* bcat2 = (float*)alloc(192 * 4);

    dim3 blk2(16, 16);

    // prep
    prep_kernel<<<(256*800 + 384*256 + 384 + 128*192 + 192 + 255) / 256, 256, 0, stream>>>(
        W_gcn1, W_d11, W_d12, b_d11, b_d12, W_d21, W_d22, b_d21, b_d22,
        Wg1T, Wcat1T, bcat1, Wcat2, bcat2);
    cast_x_kernel<<<NROWS, 256, 0, stream>>>(x, xb);
    hipMemsetAsync(Xp, 0, zero_bytes, stream);
    build_csr_kernel<<<NROWS, 256, 0, stream>>>(adj, cols, cnt, dvec);

    // stage 1 (N=8192) — bf16 storage, f32 accumulate
    gemm_mfma_kernel<__hip_bfloat16><<<dim3(4, 64), 256, 0, stream>>>(
        xb, Wg1T, nullptr, XW1b, 800, 800, 800, 256);                  // XW1 = x @ Wg1
    spmm_bf16_sliced_kernel<<<dim3(NROWS, 2), 128, 0, stream>>>(
        cols, cnt, dvec, XW1b, b_gcn1, x1b, 256, 256);                 // x1 = A@XW1 + b
    spmm_bf16_sliced_kernel<<<dim3(NROWS, 2), 128, 0, stream>>>(
        cols, cnt, dvec, x1b, nullptr, u1b, 256, 256);                 // u = A@x1
    gemm_mfma_kernel<__hip_bfloat16><<<dim3(6, 64), 256, 0, stream>>>(
        u1b, Wcat1T, bcat1, zcatb, 256, 256, 256, 384);                // zcat = u@Wcat1 + bcat1
    softmax_bf16_kernel<<<NROWS, 256, 0, stream>>>(zcatb, ASb);        // AS = softmax(s1pre)
    spmm_bf16_sliced_kernel<<<dim3(NROWS, 2), 128, 0, stream>>>(
        cols, cnt, dvec, ASb, nullptr, s1b, 256, 256);                 // s1 = A@AS

    // pooling (K=8192): MFMA bf16, atomic f32, KC=512
    gemm_atn_mfma_kernel<<<dim3(2, 4, 16), 256, 0, stream>>>(
        ASb, zcatb, Xp, 256, 128, NROWS, 512, 256, 384, 128);          // Xp = AS^T @ z1
    gemm_atn_mfma_kernel<<<dim3(4, 4, 16), 256, 0, stream>>>(
        ASb, s1b, adj2, 256, 256, NROWS, 512, 256, 256, 256);          // adj2 = AS^T @ s1

    // stage 2 (f32)
    gemm_bias_kernel<<<dim3(2, 4), blk2, 0, stream>>>(Xp, W_gcn2, nullptr, XW2,
                                                      256, 128, 128, 128, 128, 128);
    gemm_bias_kernel<<<dim3(2, 4), blk2, 0, stream>>>(adj2, XW2, b_gcn2, x2,
                                                      256, 128, 256, 256, 128, 128);
    gemm_bias_kernel<<<dim3(3, 4), blk2, 0, stream>>>(x2, Wcat2, nullptr, T2cat,
                                                      256, 192, 128, 128, 192, 192);
    gemm_bias_kernel<<<dim3(3, 4), blk2, 0, stream>>>(adj2, T2cat, bcat2, Z2cat,
                                                      256, 192, 256, 256, 192, 192);
    softmax_rows_kernel<<<256, 256, 0, stream>>>(Z2cat, 64, 192, 128);
    gemm_bias_kernel<<<dim3(1, 4), blk2, 0, stream>>>(adj2, Z2cat + 128, nullptr, AS2,
                                                      256, 64, 256, 256, 192, 64);
    gemm_atn_kernel<<<dim3(2, 1, 1), blk2, 0, stream>>>(Z2cat + 128, Z2cat, Xp2,
                                                        64, 128, 256, 256, 192, 192, 128);
    gemm_atn_kernel<<<dim3(1, 1, 1), blk2, 0, stream>>>(Z2cat + 128, AS2, adj3,
                                                        64, 64, 256, 256, 192, 64, 64);

    // stage 3 (f32)
    gemm_bias_kernel<<<dim3(2, 1), blk2, 0, stream>>>(Xp2, W_gcn3, nullptr, T30,
                                                      64, 128, 128, 128, 128, 128);
    gemm_bias_kernel<<<dim3(2, 1), blk2, 0, stream>>>(adj3, T30, b_gcn3, x3,
                                                      64, 128, 64, 64, 128, 128);
    gemm_bias_kernel<<<dim3(2, 1), blk2, 0, stream>>>(x3, W_d31, nullptr, T31,
                                                      64, 128, 128, 128, 128, 128);
    gemm_bias_kernel<<<dim3(2, 1), blk2, 0, stream>>>(adj3, T31, b_d31, z3,
                                                      64, 128, 64, 64, 128, 128);
    final_kernel<<<1, 128, 0, stream>>>(z3, W_fc, b_fc, (float*)d_out);
}

// Round 14
// 817.740 us; speedup vs baseline: 1.1593x; 1.1593x over previous
//
#include <hip/hip_runtime.h>
#include <hip/hip_bf16.h>
#include <math.h>

#define NROWS 8192
#define MAXNNZ 512

typedef __attribute__((ext_vector_type(8))) short short8v;   // 8 bf16 = 4 VGPR
typedef __attribute__((ext_vector_type(4))) float floatx4;

__device__ inline void storev(float* p, float v) { *p = v; }
__device__ inline void storev(__hip_bfloat16* p, float v) { *p = __float2bfloat16(v); }

// ---------------- CSR build: float4 scan + wave-aggregated compaction ----------------
// KEPT from round 13 (A/B isolation: SpMM reverted, this stays).
__global__ void build_csr_kernel(const float* __restrict__ adj, int* __restrict__ cols,
                                 int* __restrict__ cnt, float* __restrict__ dvec) {
    int row = blockIdx.x;
    __shared__ int lcnt;
    if (threadIdx.x == 0) lcnt = 0;
    __syncthreads();
    const float* arow = adj + (size_t)row * NROWS;
    int* crow = cols + (size_t)row * MAXNNZ;
    int tid = threadIdx.x;
    int lane = tid & 63;
#pragma unroll
    for (int j = 0; j < NROWS / 1024; ++j) {
        int c = (j * 256 + tid) * 4;
        float4 v = *reinterpret_cast<const float4*>(&arow[c]);
        float vv[4] = {v.x, v.y, v.z, v.w};
#pragma unroll
        for (int e = 0; e < 4; ++e) {
            bool nz = vv[e] != 0.0f;
            unsigned long long m = __ballot(nz);
            int tot = __popcll(m);
            if (tot) {                               // wave-uniform branch
                int pre = __popcll(m & ((1ull << lane) - 1));
                int base = 0;
                if (lane == 0) base = atomicAdd(&lcnt, tot);
                base = __shfl(base, 0);
                if (nz) {
                    int p = base + pre;
                    if (p < MAXNNZ) crow[p] = c + e;
                }
            }
        }
    }
    __syncthreads();
    if (threadIdx.x == 0) {
        int n = lcnt; if (n > MAXNNZ) n = MAXNNZ;
        cnt[row] = n;
        dvec[row] = rsqrtf((float)lcnt);
    }
}

// ---------------- cast x -> bf16, K padded 784->800 with zeros ----------------
__global__ void cast_x_kernel(const float* __restrict__ x, __hip_bfloat16* __restrict__ xb) {
    int row = blockIdx.x;
    int tid = threadIdx.x;
    const float* src = x + (size_t)row * 784;
    __hip_bfloat16* dst = xb + (size_t)row * 800;
    for (int c = tid; c < 800; c += 256)
        dst[c] = (c < 784) ? __float2bfloat16(src[c]) : __float2bfloat16(0.0f);
}

// ---------------- weight prep ----------------
__global__ void prep_kernel(const float* __restrict__ Wg1,
                            const float* __restrict__ Wd11, const float* __restrict__ Wd12,
                            const float* __restrict__ bd11, const float* __restrict__ bd12,
                            const float* __restrict__ Wd21, const float* __restrict__ Wd22,
                            const float* __restrict__ bd21, const float* __restrict__ bd22,
                            __hip_bfloat16* __restrict__ Wg1T, __hip_bfloat16* __restrict__ Wcat1T,
                            float* __restrict__ bcat1, float* __restrict__ Wcat2,
                            float* __restrict__ bcat2) {
    int idx = blockIdx.x * 256 + threadIdx.x;
    if (idx < 256 * 800) {                       // Wg1T[n][k]
        int n = idx / 800, k = idx % 800;
        Wg1T[idx] = __float2bfloat16(k < 784 ? Wg1[k * 256 + n] : 0.0f);
        return;
    }
    idx -= 256 * 800;
    if (idx < 384 * 256) {                       // Wcat1T[n][k]
        int n = idx / 256, k = idx % 256;
        float v = (n < 128) ? Wd11[k * 128 + n] : Wd12[k * 256 + (n - 128)];
        Wcat1T[idx] = __float2bfloat16(v);
        return;
    }
    idx -= 384 * 256;
    if (idx < 384) { bcat1[idx] = (idx < 128) ? bd11[idx] : bd12[idx - 128]; return; }
    idx -= 384;
    if (idx < 128 * 192) {
        int r = idx / 192, c = idx % 192;
        Wcat2[idx] = (c < 128) ? Wd21[r * 128 + c] : Wd22[r * 64 + (c - 128)];
        return;
    }
    idx -= 128 * 192;
    if (idx < 192) { bcat2[idx] = (idx < 128) ? bd21[idx] : bd22[idx - 128]; return; }
}

// ---------------- MFMA bf16 GEMM: C = A[MxK]bf16 @ (BT[NxK]bf16)^T (+bias) ----------------
// tile 128(M) x 64(N), K-step 32, 256 thr = 4 waves. (HW-verified round 10/11.)
template<typename OUT>
__global__ void gemm_mfma_kernel(const __hip_bfloat16* __restrict__ A,
                                 const __hip_bfloat16* __restrict__ BT,
                                 const float* __restrict__ bias,
                                 OUT* __restrict__ C, int K,
                                 int lda, int ldb, int ldc) {
    __shared__ __hip_bfloat16 As[128][40];   // row stride 80B
    __shared__ __hip_bfloat16 Bs[64][40];
    int tid = threadIdx.x;
    int w = tid >> 6, lane = tid & 63;
    int row0 = blockIdx.y * 128, col0 = blockIdx.x * 64;
    int lrow = lane & 15, kb = (lane >> 4) * 8;
    floatx4 acc[2][4] = {};
    int ar = tid >> 1, akh = (tid & 1) * 16;
    int bn = tid >> 2, bkh = (tid & 3) * 8;
    for (int k0 = 0; k0 < K; k0 += 32) {
        {
            const float4* src = reinterpret_cast<const float4*>(&A[(size_t)(row0 + ar) * lda + k0 + akh]);
            float4 v0 = src[0], v1 = src[1];
            *reinterpret_cast<float4*>(&As[ar][akh]) = v0;
            *reinterpret_cast<float4*>(&As[ar][akh + 8]) = v1;
        }
        {
            float4 v = *reinterpret_cast<const float4*>(&BT[(size_t)(col0 + bn) * ldb + k0 + bkh]);
            *reinterpret_cast<float4*>(&Bs[bn][bkh]) = v;
        }
        __syncthreads();
        short8v af[2], bf[4];
#pragma unroll
        for (int mi = 0; mi < 2; ++mi)
            af[mi] = *reinterpret_cast<const short8v*>(&As[w * 32 + mi * 16 + lrow][kb]);
#pragma unroll
        for (int ni = 0; ni < 4; ++ni)
            bf[ni] = *reinterpret_cast<const short8v*>(&Bs[ni * 16 + lrow][kb]);
#pragma unroll
        for (int mi = 0; mi < 2; ++mi)
#pragma unroll
            for (int ni = 0; ni < 4; ++ni)
                acc[mi][ni] = __builtin_amdgcn_mfma_f32_16x16x32_bf16(af[mi], bf[ni], acc[mi][ni], 0, 0, 0);
        __syncthreads();
    }
#pragma unroll
    for (int mi = 0; mi < 2; ++mi) {
#pragma unroll
        for (int ni = 0; ni < 4; ++ni) {
            int gcol = col0 + ni * 16 + (lane & 15);
            float bb = bias ? bias[gcol] : 0.0f;
#pragma unroll
            for (int r = 0; r < 4; ++r) {
                int grow = row0 + w * 32 + mi * 16 + (lane >> 4) * 4 + r;
                storev(&C[(size_t)grow * ldc + gcol], acc[mi][ni][r] + bb);
            }
        }
    }
}

// ---------------- MFMA bf16 pooling: C[M,N] += sum_k A[k][m]*B[k][n] (atomic f32) ----------------
__global__ void gemm_atn_mfma_kernel(const __hip_bfloat16* __restrict__ A,
                                     const __hip_bfloat16* __restrict__ B,
                                     float* __restrict__ C, int M, int N, int K, int KC,
                                     int lda, int ldb, int ldc) {
    __shared__ unsigned short At[64][40];   // [m][k]
    __shared__ unsigned short Bt[64][40];   // [n][k]
    int tid = threadIdx.x;
    int w = tid >> 6, lane = tid & 63;
    int m0 = blockIdx.y * 64, n0 = blockIdx.x * 64;
    int kbeg = blockIdx.z * KC;
    int kend = kbeg + KC; if (kend > K) kend = K;
    int lrow = lane & 15, kb = (lane >> 4) * 8;
    floatx4 acc[4] = {};
    int kk = tid >> 3;            // 0..31
    int eg = (tid & 7) * 8;       // 0..56
    for (int k0 = kbeg; k0 < kend; k0 += 32) {
        {
            unsigned short v[8];
            *reinterpret_cast<float4*>(v) = *reinterpret_cast<const float4*>(
                &A[(size_t)(k0 + kk) * lda + m0 + eg]);
#pragma unroll
            for (int e = 0; e < 8; ++e) At[eg + e][kk] = v[e];
        }
        {
            unsigned short v[8];
            *reinterpret_cast<float4*>(v) = *reinterpret_cast<const float4*>(
                &B[(size_t)(k0 + kk) * ldb + n0 + eg]);
#pragma unroll
            for (int e = 0; e < 8; ++e) Bt[eg + e][kk] = v[e];
        }
        __syncthreads();
        short8v af = *reinterpret_cast<const short8v*>(&At[w * 16 + lrow][kb]);
#pragma unroll
        for (int ni = 0; ni < 4; ++ni) {
            short8v bfr = *reinterpret_cast<const short8v*>(&Bt[ni * 16 + lrow][kb]);
            acc[ni] = __builtin_amdgcn_mfma_f32_16x16x32_bf16(af, bfr, acc[ni], 0, 0, 0);
        }
        __syncthreads();
    }
#pragma unroll
    for (int ni = 0; ni < 4; ++ni) {
        int gcol = n0 + ni * 16 + lrow;
#pragma unroll
        for (int r = 0; r < 4; ++r) {
            int grow = m0 + w * 16 + (lane >> 4) * 4 + r;
            atomicAdd(&C[(size_t)grow * ldc + gcol], acc[ni][r]);
        }
    }
}

// ---------------- col-sliced SpMM (bf16 gather, LDS-staged metadata — round-11 version) ----------------
// REVERTED from round 13's scalar-metadata version (that was a +128us regression:
// dependent s_load chains per wave beat the amortized cooperative LDS staging).
__global__ void spmm_bf16_sliced_kernel(const int* __restrict__ cols, const int* __restrict__ cnt,
                                        const float* __restrict__ dvec,
                                        const __hip_bfloat16* __restrict__ H,
                                        const float* __restrict__ bias,
                                        __hip_bfloat16* __restrict__ out,
                                        int ldh, int ldo) {
    int row = blockIdx.x;
    int cb = blockIdx.y * 128;
    int tid = threadIdx.x;
    __shared__ int sidx[MAXNNZ];
    __shared__ float sw[MAXNNZ];
    int n = cnt[row];
    const int* crow = cols + (size_t)row * MAXNNZ;
    for (int i = tid; i < n; i += 128) {
        int c = crow[i];
        sidx[i] = c * ldh + cb;
        sw[i] = dvec[c];
    }
    __syncthreads();
    float acc = 0.0f;
    int i = 0;
    for (; i + 8 <= n; i += 8) {     // 8 loads in flight
        float h0 = __bfloat162float(H[sidx[i]   + tid]);
        float h1 = __bfloat162float(H[sidx[i+1] + tid]);
        float h2 = __bfloat162float(H[sidx[i+2] + tid]);
        float h3 = __bfloat162float(H[sidx[i+3] + tid]);
        float h4 = __bfloat162float(H[sidx[i+4] + tid]);
        float h5 = __bfloat162float(H[sidx[i+5] + tid]);
        float h6 = __bfloat162float(H[sidx[i+6] + tid]);
        float h7 = __bfloat162float(H[sidx[i+7] + tid]);
        acc += sw[i]*h0 + sw[i+1]*h1 + sw[i+2]*h2 + sw[i+3]*h3
             + sw[i+4]*h4 + sw[i+5]*h5 + sw[i+6]*h6 + sw[i+7]*h7;
    }
    for (; i < n; i++) acc += sw[i] * __bfloat162float(H[sidx[i] + tid]);
    float r = dvec[row] * acc;
    if (bias) r += bias[cb + tid];
    out[(size_t)row * ldo + cb + tid] = __float2bfloat16(r);
}

// ---------------- softmax over bf16 row (256 cols), bf16 out ----------------
__global__ void softmax_bf16_kernel(const __hip_bfloat16* __restrict__ in,
                                    __hip_bfloat16* __restrict__ out) {
    int row = blockIdx.x;
    int tid = threadIdx.x;
    __shared__ float red[256];
    float v = __bfloat162float(in[(size_t)row * 384 + 128 + tid]);
    red[tid] = v; __syncthreads();
    for (int s = 128; s > 0; s >>= 1) {
        if (tid < s) red[tid] = fmaxf(red[tid], red[tid + s]);
        __syncthreads();
    }
    float m = red[0]; __syncthreads();
    float e = expf(v - m);
    red[tid] = e; __syncthreads();
    for (int s = 128; s > 0; s >>= 1) {
        if (tid < s) red[tid] += red[tid + s];
        __syncthreads();
    }
    out[(size_t)row * 256 + tid] = __float2bfloat16(e / red[0]);
}

// ---------------- Tiled f32 GEMM (stage 2/3) ----------------
__global__ void gemm_bias_kernel(const float* __restrict__ A, const float* __restrict__ B,
                                 const float* __restrict__ bias, float* __restrict__ C,
                                 int M, int N, int K, int lda, int ldb, int ldc) {
    __shared__ float As[16][68];
    __shared__ float Bs[16][68];
    int tx = threadIdx.x, ty = threadIdx.y;
    int tid = ty * 16 + tx;
    int row0 = blockIdx.y * 64, col0 = blockIdx.x * 64;
    int am = tid >> 2, ak = (tid & 3) * 4;
    int bk = tid >> 4, bn = (tid & 15) * 4;
    float acc[4][4] = {};
    for (int k0 = 0; k0 < K; k0 += 16) {
        int gm = row0 + am;
        float4 va = make_float4(0.f, 0.f, 0.f, 0.f);
        if (gm < M) va = *reinterpret_cast<const float4*>(&A[(size_t)gm * lda + k0 + ak]);
        As[ak + 0][am] = va.x; As[ak + 1][am] = va.y;
        As[ak + 2][am] = va.z; As[ak + 3][am] = va.w;
        float4 vb = *reinterpret_cast<const float4*>(&B[(size_t)(k0 + bk) * ldb + col0 + bn]);
        *reinterpret_cast<float4*>(&Bs[bk][bn]) = vb;
        __syncthreads();
#pragma unroll
        for (int k = 0; k < 16; ++k) {
            float4 a = *reinterpret_cast<const float4*>(&As[k][ty * 4]);
            float4 b = *reinterpret_cast<const float4*>(&Bs[k][tx * 4]);
            float av[4] = {a.x, a.y, a.z, a.w};
            float bv[4] = {b.x, b.y, b.z, b.w};
#pragma unroll
            for (int i = 0; i < 4; ++i)
#pragma unroll
                for (int j = 0; j < 4; ++j)
                    acc[i][j] += av[i] * bv[j];
        }
        __syncthreads();
    }
    float4 bb = make_float4(0.f, 0.f, 0.f, 0.f);
    if (bias) bb = *reinterpret_cast<const float4*>(&bias[col0 + tx * 4]);
#pragma unroll
    for (int i = 0; i < 4; ++i) {
        int gm = row0 + ty * 4 + i;
        if (gm >= M) continue;
        float4 v = make_float4(acc[i][0] + bb.x, acc[i][1] + bb.y,
                               acc[i][2] + bb.z, acc[i][3] + bb.w);
        *reinterpret_cast<float4*>(&C[(size_t)gm * ldc + col0 + tx * 4]) = v;
    }
}

// ---------------- f32 A^T pooling (stage-2 small sizes only) ----------------
__global__ void gemm_atn_kernel(const float* __restrict__ A, const float* __restrict__ B,
                                float* __restrict__ C, int M, int N, int K, int KC,
                                int lda, int ldb, int ldc) {
    __shared__ float As[16][68];
    __shared__ float Bs[16][68];
    int tx = threadIdx.x, ty = threadIdx.y;
    int tid = ty * 16 + tx;
    int row0 = blockIdx.y * 64, col0 = blockIdx.x * 64;
    int kbeg = blockIdx.z * KC;
    int kend = kbeg + KC; if (kend > K) kend = K;
    int ka = tid >> 4, m4 = (tid & 15) * 4;
    int bk = tid >> 4, bn = (tid & 15) * 4;
    float acc[4][4] = {};
    for (int k0 = kbeg; k0 < kend; k0 += 16) {
        int gm = row0 + m4;
        float4 va = make_float4(0.f, 0.f, 0.f, 0.f);
        if (gm < M) va = *reinterpret_cast<const float4*>(&A[(size_t)(k0 + ka) * lda + gm]);
        *reinterpret_cast<float4*>(&As[ka][m4]) = va;
        float4 vb = *reinterpret_cast<const float4*>(&B[(size_t)(k0 + bk) * ldb + col0 + bn]);
        *reinterpret_cast<float4*>(&Bs[bk][bn]) = vb;
        __syncthreads();
#pragma unroll
        for (int k = 0; k < 16; ++k) {
            float4 a = *reinterpret_cast<const float4*>(&As[k][ty * 4]);
            float4 b = *reinterpret_cast<const float4*>(&Bs[k][tx * 4]);
            float av[4] = {a.x, a.y, a.z, a.w};
            float bv[4] = {b.x, b.y, b.z, b.w};
#pragma unroll
            for (int i = 0; i < 4; ++i)
#pragma unroll
                for (int j = 0; j < 4; ++j)
                    acc[i][j] += av[i] * bv[j];
        }
        __syncthreads();
    }
#pragma unroll
    for (int i = 0; i < 4; ++i) {
        int gm = row0 + ty * 4 + i;
        if (gm >= M) continue;
#pragma unroll
        for (int j = 0; j < 4; ++j)
            atomicAdd(&C[(size_t)gm * ldc + col0 + tx * 4 + j], acc[i][j]);
    }
}

// ---------------- row softmax on strided f32 view, in place ----------------
__global__ void softmax_rows_kernel(float* __restrict__ data, int NC, int ld, int off) {
    int row = blockIdx.x;
    float* p = data + (size_t)row * ld + off;
    __shared__ float red[256];
    int tid = threadIdx.x;
    float m = -INFINITY;
    for (int c = tid; c < NC; c += 256) m = fmaxf(m, p[c]);
    red[tid] = m; __syncthreads();
    for (int s = 128; s > 0; s >>= 1) {
        if (tid < s) red[tid] = fmaxf(red[tid], red[tid + s]);
        __syncthreads();
    }
    m = red[0]; __syncthreads();
    float sum = 0.0f;
    for (int c = tid; c < NC; c += 256) sum += expf(p[c] - m);
    red[tid] = sum; __syncthreads();
    for (int s = 128; s > 0; s >>= 1) {
        if (tid < s) red[tid] += red[tid + s];
        __syncthreads();
    }
    float inv = 1.0f / red[0];
    for (int c = tid; c < NC; c += 256) p[c] = expf(p[c] - m) * inv;
}

// ---------------- final: colsum(z3) -> fc -> log_softmax ----------------
__global__ void final_kernel(const float* __restrict__ z3, const float* __restrict__ Wfc,
                             const float* __restrict__ bfc, float* __restrict__ out) {
    __shared__ float v[128];
    __shared__ float o[10];
    int tid = threadIdx.x;
    float a = 0.0f;
#pragma unroll
    for (int i = 0; i < 64; i++) a += z3[i * 128 + tid];
    v[tid] = a;
    __syncthreads();
    if (tid < 10) {
        float s = 0.0f;
        for (int k = 0; k < 128; k++) s += v[k] * Wfc[k * 10 + tid];
        o[tid] = s + bfc[tid];
    }
    __syncthreads();
    if (tid == 0) {
        float m = -INFINITY;
        for (int c = 0; c < 10; c++) m = fmaxf(m, o[c]);
        float s = 0.0f;
        for (int c = 0; c < 10; c++) s += expf(o[c] - m);
        float lse = m + logf(s);
        for (int c = 0; c < 10; c++) out[c] = o[c] - lse;
    }
}

extern "C" void kernel_launch(void* const* d_in, const int* in_sizes, int n_in,
                              void* d_out, int out_size, void* d_ws, size_t ws_size,
                              hipStream_t stream) {
    const float* x      = (const float*)d_in[0];
    const float* adj    = (const float*)d_in[1];
    const float* W_gcn1 = (const float*)d_in[2];
    const float* b_gcn1 = (const float*)d_in[3];
    const float* W_d11  = (const float*)d_in[4];
    const float* b_d11  = (const float*)d_in[5];
    const float* W_d12  = (const float*)d_in[6];
    const float* b_d12  = (const float*)d_in[7];
    const float* W_gcn2 = (const float*)d_in[8];
    const float* b_gcn2 = (const float*)d_in[9];
    const float* W_d21  = (const float*)d_in[10];
    const float* b_d21  = (const float*)d_in[11];
    const float* W_d22  = (const float*)d_in[12];
    const float* b_d22  = (const float*)d_in[13];
    const float* W_gcn3 = (const float*)d_in[14];
    const float* b_gcn3 = (const float*)d_in[15];
    const float* W_d31  = (const float*)d_in[16];
    const float* b_d31  = (const float*)d_in[17];
    // W_d32/b_d32 unused: softmax over a length-1 axis == 1
    const float* W_fc   = (const float*)d_in[20];
    const float* b_fc   = (const float*)d_in[21];

    char* ws = (char*)d_ws;
    size_t off = 0;
    auto alloc = [&](size_t bytes) -> char* {
        char* p = ws + off;
        off = (off + bytes + 255) & ~(size_t)255;
        return p;
    };
    int*   cols  = (int*)  alloc((size_t)NROWS * MAXNNZ * 4);
    int*   cnt   = (int*)  alloc((size_t)NROWS * 4);
    float* dvec  = (float*)alloc((size_t)NROWS * 4);
    __hip_bfloat16* xb     = (__hip_bfloat16*)alloc((size_t)NROWS * 800 * 2);
    __hip_bfloat16* Wg1T   = (__hip_bfloat16*)alloc(256 * 800 * 2);
    __hip_bfloat16* Wcat1T = (__hip_bfloat16*)alloc(384 * 256 * 2);
    __hip_bfloat16* XW1b   = (__hip_bfloat16*)alloc((size_t)NROWS * 256 * 2);
    __hip_bfloat16* x1b    = (__hip_bfloat16*)alloc((size_t)NROWS * 256 * 2);
    __hip_bfloat16* u1b    = (__hip_bfloat16*)alloc((size_t)NROWS * 256 * 2);
    __hip_bfloat16* zcatb  = (__hip_bfloat16*)alloc((size_t)NROWS * 384 * 2);  // [z1(128)|s1pre(256)]
    __hip_bfloat16* ASb    = (__hip_bfloat16*)alloc((size_t)NROWS * 256 * 2);
    __hip_bfloat16* s1b    = (__hip_bfloat16*)alloc((size_t)NROWS * 256 * 2);
    // pooled-zero region (one memset)
    float* Xp    = (float*)alloc(256 * 128 * 4);
    float* adj2  = (float*)alloc(256 * 256 * 4);
    float* Xp2   = (float*)alloc(64 * 128 * 4);
    float* adj3  = (float*)alloc(64 * 64 * 4);
    size_t zero_bytes = 256*128*4 + 256*256*4 + 64*128*4 + 64*64*4;
    float* XW2   = (float*)alloc(256 * 128 * 4);
    float* x2    = (float*)alloc(256 * 128 * 4);
    float* T2cat = (float*)alloc(256 * 192 * 4);
    float* Z2cat = (float*)alloc(256 * 192 * 4);
    float* AS2   = (float*)alloc(256 * 64 * 4);
    float* T30   = (float*)alloc(64 * 128 * 4);
    float* x3    = (float*)alloc(64 * 128 * 4);
    float* T31   = (float*)alloc(64 * 128 * 4);
    float* z3    = (float*)alloc(64 * 128 * 4);
    float* Wcat2 = (float*)alloc(128 * 192 * 4);
    float* bcat1 = (float*)alloc(384 * 4);
    float* bcat2 = (float*)alloc(192 * 4);

    dim3 blk2(16, 16);

    // prep
    prep_kernel<<<(256*800 + 384*256 + 384 + 128*192 + 192 + 255) / 256, 256, 0, stream>>>(
        W_gcn1, W_d11, W_d12, b_d11, b_d12, W_d21, W_d22, b_d21, b_d22,
        Wg1T, Wcat1T, bcat1, Wcat2, bcat2);
    cast_x_kernel<<<NROWS, 256, 0, stream>>>(x, xb);
    hipMemsetAsync(Xp, 0, zero_bytes, stream);
    build_csr_kernel<<<NROWS, 256, 0, stream>>>(adj, cols, cnt, dvec);

    // stage 1 (N=8192) — bf16 storage, f32 accumulate
    gemm_mfma_kernel<__hip_bfloat16><<<dim3(4, 64), 256, 0, stream>>>(
        xb, Wg1T, nullptr, XW1b, 800, 800, 800, 256);                  // XW1 = x @ Wg1
    spmm_bf16_sliced_kernel<<<dim3(NROWS, 2), 128, 0, stream>>>(
        cols, cnt, dvec, XW1b, b_gcn1, x1b, 256, 256);                 // x1 = A@XW1 + b
    spmm_bf16_sliced_kernel<<<dim3(NROWS, 2), 128, 0, stream>>>(
        cols, cnt, dvec, x1b, nullptr, u1b, 256, 256);                 // u = A@x1
    gemm_mfma_kernel<__hip_bfloat16><<<dim3(6, 64), 256, 0, stream>>>(
        u1b, Wcat1T, bcat1, zcatb, 256, 256, 256, 384);                // zcat = u@Wcat1 + bcat1
    softmax_bf16_kernel<<<NROWS, 256, 0, stream>>>(zcatb, ASb);        // AS = softmax(s1pre)
    spmm_bf16_sliced_kernel<<<dim3(NROWS, 2), 128, 0, stream>>>(
        cols, cnt, dvec, ASb, nullptr, s1b, 256, 256);                 // s1 = A@AS

    // pooling (K=8192): MFMA bf16, atomic f32, KC=512
    gemm_atn_mfma_kernel<<<dim3(2, 4, 16), 256, 0, stream>>>(
        ASb, zcatb, Xp, 256, 128, NROWS, 512, 256, 384, 128);          // Xp = AS^T @ z1
    gemm_atn_mfma_kernel<<<dim3(4, 4, 16), 256, 0, stream>>>(
        ASb, s1b, adj2, 256, 256, NROWS, 512, 256, 256, 256);          // adj2 = AS^T @ s1

    // stage 2 (f32)
    gemm_bias_kernel<<<dim3(2, 4), blk2, 0, stream>>>(Xp, W_gcn2, nullptr, XW2,
                                                      256, 128, 128, 128, 128, 128);
    gemm_bias_kernel<<<dim3(2, 4), blk2, 0, stream>>>(adj2, XW2, b_gcn2, x2,
                                                      256, 128, 256, 256, 128, 128);
    gemm_bias_kernel<<<dim3(3, 4), blk2, 0, stream>>>(x2, Wcat2, nullptr, T2cat,
                                                      256, 192, 128, 128, 192, 192);
    gemm_bias_kernel<<<dim3(3, 4), blk2, 0, stream>>>(adj2, T2cat, bcat2, Z2cat,
                                                      256, 192, 256, 256, 192, 192);
    softmax_rows_kernel<<<256, 256, 0, stream>>>(Z2cat, 64, 192, 128);
    gemm_bias_kernel<<<dim3(1, 4), blk2, 0, stream>>>(adj2, Z2cat + 128, nullptr, AS2,
                                                      256, 64, 256, 256, 192, 64);
    gemm_atn_kernel<<<dim3(2, 1, 1), blk2, 0, stream>>>(Z2cat + 128, Z2cat, Xp2,
                                                        64, 128, 256, 256, 192, 192, 128);
    gemm_atn_kernel<<<dim3(1, 1, 1), blk2, 0, stream>>>(Z2cat + 128, AS2, adj3,
                                                        64, 64, 256, 256, 192, 64, 64);

    // stage 3 (f32)
    gemm_bias_kernel<<<dim3(2, 1), blk2, 0, stream>>>(Xp2, W_gcn3, nullptr, T30,
                                                      64, 128, 128, 128, 128, 128);
    gemm_bias_kernel<<<dim3(2, 1), blk2, 0, stream>>>(adj3, T30, b_gcn3, x3,
                                                      64, 128, 64, 64, 128, 128);
    gemm_bias_kernel<<<dim3(2, 1), blk2, 0, stream>>>(x3, W_d31, nullptr, T31,
                                                      64, 128, 128, 128, 128, 128);
    gemm_bias_kernel<<<dim3(2, 1), blk2, 0, stream>>>(adj3, T31, b_d31, z3,
                                                      64, 128, 64, 64, 128, 128);
    final_kernel<<<1, 128, 0, stream>>>(z3, W_fc, b_fc, (float*)d_out);
}